// Round 2
// baseline (79.668 us; speedup 1.0000x reference)
//
#include <hip/hip_runtime.h>

// Problem constants (N=4, D=H=W=96, corner grid G=97)
#define NB   4
#define DIM  96
#define HWp  (96*96)           // 9216
#define DHW  (96*96*96)        // 884736
#define G    97
#define GG   (97*97)           // 9409

#define VERTS_ELEMS 2738019u   // 97^3 * 3
#define FACES_ELEMS 31850496u  // 6*DHW*6
#define MASK_PAIRS  21233664u  // 4*6*DHW
#define FACES_OFF   2738019u
#define MASK_OFF    34588515u  // VERTS_ELEMS + FACES_ELEMS

// _TRI corner-id deltas: delta = oz*9409 + oy*97 + ox; per quad q the 6
// triangle-vertex elements are {d0,d1,d2, d1,d2,d3} of _QUAD[q].
__constant__ int c_tri[6][6] = {
    {0,    1,    97,   1,    97,   98},    // q0 (z-)
    {9409, 9410, 9506, 9410, 9506, 9507},  // q1 (z+)
    {9409, 9410, 0,    9410, 0,    1},     // q2 (y-)
    {97,   98,   9506, 98,   9506, 9507},  // q3 (y+)
    {9409, 0,    9506, 0,    9506, 97},    // q4 (x-)
    {1,    9410, 98,   9410, 98,   9507},  // q5 (x+)
};

__global__ void verts_k(float* __restrict__ out) {
    unsigned idx = blockIdx.x * 256u + threadIdx.x;
    if (idx >= VERTS_ELEMS) return;
    unsigned v = idx / 3u;
    unsigned c = idx - v * 3u;
    unsigned z = v / (unsigned)GG;
    unsigned r = v - z * (unsigned)GG;
    unsigned y = r / (unsigned)G;
    unsigned x = r - y * (unsigned)G;
    unsigned coord = (c == 0u) ? z : ((c == 1u) ? y : x);
    out[idx] = (float)coord - 0.5f;
}

__global__ void faces_k(float* __restrict__ out) {
    unsigned idx = blockIdx.x * 256u + threadIdx.x;
    if (idx >= FACES_ELEMS) return;
    unsigned quad = idx / 6u;
    unsigned e    = idx - quad * 6u;
    unsigned q    = quad / (unsigned)DHW;
    unsigned vox  = quad - q * (unsigned)DHW;
    unsigned z = vox / (unsigned)HWp;
    unsigned r = vox - z * (unsigned)HWp;
    unsigned y = r / 96u;
    unsigned x = r - y * 96u;
    unsigned base = (z * (unsigned)G + y) * (unsigned)G + x;
    unsigned cid  = base + (unsigned)c_tri[q][e];
    out[FACES_OFF + idx] = (float)cid;   // < 2^24, exact in f32
}

__global__ void mask_k(const float* __restrict__ p, float* __restrict__ out) {
    unsigned pairi = blockIdx.x * 256u + threadIdx.x;   // (n, q, vox)
    if (pairi >= MASK_PAIRS) return;
    unsigned vox = pairi % (unsigned)DHW;
    unsigned nq  = pairi / (unsigned)DHW;
    unsigned q   = nq % 6u;
    unsigned n   = nq / 6u;
    unsigned z = vox / (unsigned)HWp;
    unsigned r = vox - z * (unsigned)HWp;
    unsigned y = r / 96u;
    unsigned x = r - y * 96u;

    // neighbor with wraparound along axis q>>1, direction (q&1)? +1 : -1
    int nz = (int)z, ny = (int)y, nx = (int)x;
    unsigned axis = q >> 1;
    int dir = (q & 1u) ? 1 : -1;
    if (axis == 0u) { nz += dir; nz = (nz < 0) ? DIM - 1 : ((nz >= DIM) ? 0 : nz); }
    else if (axis == 1u) { ny += dir; ny = (ny < 0) ? DIM - 1 : ((ny >= DIM) ? 0 : ny); }
    else { nx += dir; nx = (nx < 0) ? DIM - 1 : ((nx >= DIM) ? 0 : nx); }
    unsigned nvox = (unsigned)nz * (unsigned)HWp + (unsigned)ny * 96u + (unsigned)nx;

    const float* pb = p + (size_t)n * (unsigned)DHW;
    bool self = pb[vox]  > 0.5f;
    bool nb   = pb[nvox] > 0.5f;
    float val = (self && !nb) ? 1.0f : 0.0f;

    size_t o = (size_t)MASK_OFF + (size_t)pairi * 2u;
    out[o]     = val;
    out[o + 1] = val;
}

extern "C" void kernel_launch(void* const* d_in, const int* in_sizes, int n_in,
                              void* d_out, int out_size, void* d_ws, size_t ws_size,
                              hipStream_t stream) {
    const float* probas = (const float*)d_in[0];
    float* out = (float*)d_out;

    verts_k<<<(VERTS_ELEMS + 255u) / 256u, 256, 0, stream>>>(out);
    faces_k<<<(FACES_ELEMS + 255u) / 256u, 256, 0, stream>>>(out);
    mask_k <<<(MASK_PAIRS  + 255u) / 256u, 256, 0, stream>>>(probas, out);
}

// Round 3
// 60.483 us; speedup vs baseline: 1.3172x; 1.3172x over previous
//
#include <hip/hip_runtime.h>

// Problem constants (N=4, D=H=W=96, corner grid G=97)
#define DHW   884736u          // 96^3
#define HWp   9216u            // 96^2
#define VERTS_ELEMS 2738019u   // 97^3 * 3
#define FACES_OFF   2738019u
#define MASK_OFF    34588515u  // VERTS + FACES elems

#define MASK_GROUPS  5308416u  // 4*6*DHW / 4 voxels-per-thread
#define FACES_QUADS  5308416u  // 6*DHW
#define VERTS_GROUPS 684505u   // ceil(VERTS_ELEMS/4)

#define MASK_BLOCKS  20736u    // MASK_GROUPS/256
#define FACES_BLOCKS 20736u    // FACES_QUADS/256
#define VERTS_BLOCKS 2674u     // ceil(VERTS_GROUPS/256)
#define TOTAL_BLOCKS (MASK_BLOCKS + FACES_BLOCKS + VERTS_BLOCKS)

// _TRI corner-id deltas: delta = oz*9409 + oy*97 + ox; per quad q the 6
// triangle-vertex elements are {d0,d1,d2, d1,d2,d3} of _QUAD[q].
__constant__ int c_tri[6][6] = {
    {0,    1,    97,   1,    97,   98},    // q0 (z-)
    {9409, 9410, 9506, 9410, 9506, 9507},  // q1 (z+)
    {9409, 9410, 0,    9410, 0,    1},     // q2 (y-)
    {97,   98,   9506, 98,   9506, 9507},  // q3 (y+)
    {9409, 0,    9506, 0,    9506, 97},    // q4 (x-)
    {1,    9410, 98,   9410, 98,   9507},  // q5 (x+)
};

// 4-byte-aligned vector stores (region offsets are odd floats; CDNA
// global multi-dword ops need only dword alignment).
typedef struct __attribute__((packed, aligned(4))) { float x, y, z, w; } f4a;
typedef struct __attribute__((packed, aligned(4))) { float x, y; } f2a;

__global__ void __launch_bounds__(256) cubify_k(const float* __restrict__ p,
                                                float* __restrict__ out) {
    const unsigned bid = blockIdx.x, tid = threadIdx.x;

    if (bid < MASK_BLOCKS) {
        // ---- face_mask: one thread = 4 voxels (same n,q; x = 0 mod 4) ----
        unsigned g    = bid * 256u + tid;
        unsigned nq   = g / 221184u;           // DHW/4 groups per (n,q)
        unsigned voxg = g - nq * 221184u;
        unsigned vox  = voxg * 4u;
        unsigned n = nq / 6u, q = nq - n * 6u; // q block-uniform (221184%256==0)
        unsigned z = vox / HWp;
        unsigned r = vox - z * HWp;
        unsigned y = r / 96u;
        unsigned x = r - y * 96u;

        const float* pb = p + (size_t)n * DHW;
        float4 s = *(const float4*)(pb + vox); // 16B aligned
        float n0, n1, n2, n3;
        unsigned axis = q >> 1;
        int dir = (q & 1u) ? 1 : -1;
        if (axis == 0u) {
            int nz = (int)z + dir; nz = nz < 0 ? 95 : (nz > 95 ? 0 : nz);
            float4 nb = *(const float4*)(pb + (unsigned)nz * HWp + y * 96u + x);
            n0 = nb.x; n1 = nb.y; n2 = nb.z; n3 = nb.w;
        } else if (axis == 1u) {
            int ny = (int)y + dir; ny = ny < 0 ? 95 : (ny > 95 ? 0 : ny);
            float4 nb = *(const float4*)(pb + z * HWp + (unsigned)ny * 96u + x);
            n0 = nb.x; n1 = nb.y; n2 = nb.z; n3 = nb.w;
        } else if (dir == 1) {
            float e = pb[(x == 92u) ? vox - 92u : vox + 4u];
            n0 = s.y; n1 = s.z; n2 = s.w; n3 = e;
        } else {
            float e = pb[(x == 0u) ? vox + 95u : vox - 1u];
            n0 = e; n1 = s.x; n2 = s.y; n3 = s.z;
        }
        float v0 = (s.x > 0.5f && !(n0 > 0.5f)) ? 1.0f : 0.0f;
        float v1 = (s.y > 0.5f && !(n1 > 0.5f)) ? 1.0f : 0.0f;
        float v2 = (s.z > 0.5f && !(n2 > 0.5f)) ? 1.0f : 0.0f;
        float v3 = (s.w > 0.5f && !(n3 > 0.5f)) ? 1.0f : 0.0f;

        float* o = out + (size_t)MASK_OFF + (size_t)g * 8u;
        *(f4a*)(o)     = (f4a){v0, v0, v1, v1};
        *(f4a*)(o + 4) = (f4a){v2, v2, v3, v3};

    } else if (bid < MASK_BLOCKS + FACES_BLOCKS) {
        // ---- faces: one thread = one quad (6 ids) ----
        unsigned quad = (bid - MASK_BLOCKS) * 256u + tid;
        unsigned q   = quad / DHW;             // block-uniform (DHW%256==0)
        unsigned vox = quad - q * DHW;
        unsigned z = vox / HWp;
        unsigned r = vox - z * HWp;
        unsigned y = r / 96u;
        unsigned x = r - y * 96u;
        unsigned base = (z * 97u + y) * 97u + x;
        const int* t = c_tri[q];
        float* o = out + (size_t)FACES_OFF + (size_t)quad * 6u;
        *(f4a*)(o)     = (f4a){(float)(base + t[0]), (float)(base + t[1]),
                               (float)(base + t[2]), (float)(base + t[3])};
        *(f2a*)(o + 4) = (f2a){(float)(base + t[4]), (float)(base + t[5])};

    } else {
        // ---- verts: one thread = 4 elements ----
        unsigned i4 = ((bid - (MASK_BLOCKS + FACES_BLOCKS)) * 256u + tid) * 4u;
        if (i4 + 3u < VERTS_ELEMS) {
            float vals[4];
#pragma unroll
            for (int j = 0; j < 4; ++j) {
                unsigned idx = i4 + (unsigned)j;
                unsigned v = idx / 3u;
                unsigned c = idx - v * 3u;
                unsigned z = v / 9409u;
                unsigned r = v - z * 9409u;
                unsigned y = r / 97u;
                unsigned x = r - y * 97u;
                unsigned coord = (c == 0u) ? z : ((c == 1u) ? y : x);
                vals[j] = (float)coord - 0.5f;
            }
            *(float4*)(out + i4) = make_float4(vals[0], vals[1], vals[2], vals[3]);
        } else if (i4 < VERTS_ELEMS) {
            for (unsigned idx = i4; idx < VERTS_ELEMS; ++idx) {
                unsigned v = idx / 3u;
                unsigned c = idx - v * 3u;
                unsigned z = v / 9409u;
                unsigned r = v - z * 9409u;
                unsigned y = r / 97u;
                unsigned x = r - y * 97u;
                unsigned coord = (c == 0u) ? z : ((c == 1u) ? y : x);
                out[idx] = (float)coord - 0.5f;
            }
        }
    }
}

extern "C" void kernel_launch(void* const* d_in, const int* in_sizes, int n_in,
                              void* d_out, int out_size, void* d_ws, size_t ws_size,
                              hipStream_t stream) {
    const float* probas = (const float*)d_in[0];
    float* out = (float*)d_out;
    cubify_k<<<TOTAL_BLOCKS, 256, 0, stream>>>(probas, out);
}

// Round 4
// 59.196 us; speedup vs baseline: 1.3458x; 1.0218x over previous
//
#include <hip/hip_runtime.h>

// Problem constants (N=4, D=H=W=96, corner grid G=97)
#define DHW   884736u          // 96^3
#define HWp   9216u            // 96^2
#define VERTS_ELEMS 2738019u   // 97^3 * 3
#define FACES_OFF   2738019u
#define MASK_OFF    34588515u  // VERTS + FACES elems

#define MASK_BLOCKS  3456u     // 4*DHW/4 voxel-groups / 256
#define FACES_BLOCKS 20736u    // 6*DHW quads / 256
#define VERTS_BLOCKS 2674u     // ceil(ceil(VERTS_ELEMS/4)/256)
#define TOTAL_BLOCKS (MASK_BLOCKS + FACES_BLOCKS + VERTS_BLOCKS)

// _TRI corner-id deltas: delta = oz*9409 + oy*97 + ox; per quad q the 6
// triangle-vertex elements are {d0,d1,d2, d1,d2,d3} of _QUAD[q].
__constant__ int c_tri[6][6] = {
    {0,    1,    97,   1,    97,   98},    // q0 (z-)
    {9409, 9410, 9506, 9410, 9506, 9507},  // q1 (z+)
    {9409, 9410, 0,    9410, 0,    1},     // q2 (y-)
    {97,   98,   9506, 98,   9506, 9507},  // q3 (y+)
    {9409, 0,    9506, 0,    9506, 97},    // q4 (x-)
    {1,    9410, 98,   9410, 98,   9507},  // q5 (x+)
};

// 4-byte-aligned vector stores (region offsets are odd floats; CDNA
// global multi-dword ops need only dword alignment).
typedef struct __attribute__((packed, aligned(4))) { float x, y, z, w; } f4a;
typedef struct __attribute__((packed, aligned(4))) { float x, y; } f2a;

__global__ void __launch_bounds__(256) cubify_k(const float* __restrict__ p,
                                                float* __restrict__ out) {
    const unsigned bid = blockIdx.x, tid = threadIdx.x;

    if (bid < MASK_BLOCKS) {
        // ---- face_mask: one thread = 4 voxels (x%4==0) x ALL 6 directions ----
        unsigned g    = bid * 256u + tid;      // (n, voxg)
        unsigned n    = g / 221184u;           // DHW/4; block-uniform (864 blk/n)
        unsigned voxg = g - n * 221184u;
        unsigned vox  = voxg * 4u;
        unsigned z = vox / HWp;
        unsigned r = vox - z * HWp;
        unsigned y = r / 96u;
        unsigned x = r - y * 96u;              // x%4==0, group never crosses a row

        const float* pb = p + (size_t)n * DHW;
        float4 s = *(const float4*)(pb + vox);           // self, 16B aligned
        bool s0 = s.x > 0.5f, s1 = s.y > 0.5f, s2 = s.z > 0.5f, s3 = s.w > 0.5f;

        unsigned zm = (z == 0u) ? 95u : z - 1u, zp = (z == 95u) ? 0u : z + 1u;
        unsigned ym = (y == 0u) ? 95u : y - 1u, yp = (y == 95u) ? 0u : y + 1u;
        unsigned rowoff = y * 96u + x;
        float4 nzm = *(const float4*)(pb + zm * HWp + rowoff);
        float4 nzp = *(const float4*)(pb + zp * HWp + rowoff);
        float4 nym = *(const float4*)(pb + z * HWp + ym * 96u + x);
        float4 nyp = *(const float4*)(pb + z * HWp + yp * 96u + x);
        float exm = pb[(x == 0u)  ? vox + 95u : vox - 1u];   // x-1 (wrap)
        float exp_ = pb[(x == 92u) ? vox - 92u : vox + 4u];  // x+4 (wrap)

        float* ob = out + (size_t)MASK_OFF + ((size_t)(n * 6u) * DHW + vox) * 2u;
        auto emit = [&](unsigned q, float a, float b, float c, float d) {
            float v0 = (s0 && !(a > 0.5f)) ? 1.0f : 0.0f;
            float v1 = (s1 && !(b > 0.5f)) ? 1.0f : 0.0f;
            float v2 = (s2 && !(c > 0.5f)) ? 1.0f : 0.0f;
            float v3 = (s3 && !(d > 0.5f)) ? 1.0f : 0.0f;
            float* o = ob + (size_t)q * (DHW * 2u);
            *(f4a*)(o)     = (f4a){v0, v0, v1, v1};
            *(f4a*)(o + 4) = (f4a){v2, v2, v3, v3};
        };
        emit(0u, nzm.x, nzm.y, nzm.z, nzm.w);   // z-1
        emit(1u, nzp.x, nzp.y, nzp.z, nzp.w);   // z+1
        emit(2u, nym.x, nym.y, nym.z, nym.w);   // y-1
        emit(3u, nyp.x, nyp.y, nyp.z, nyp.w);   // y+1
        emit(4u, exm,  s.x,  s.y,  s.z);        // x-1
        emit(5u, s.y,  s.z,  s.w,  exp_);       // x+1

    } else if (bid < MASK_BLOCKS + FACES_BLOCKS) {
        // ---- faces: one thread = one quad (6 ids) ----
        unsigned quad = (bid - MASK_BLOCKS) * 256u + tid;
        unsigned q   = quad / DHW;             // block-uniform (DHW%256==0)
        unsigned vox = quad - q * DHW;
        unsigned z = vox / HWp;
        unsigned r = vox - z * HWp;
        unsigned y = r / 96u;
        unsigned x = r - y * 96u;
        unsigned base = (z * 97u + y) * 97u + x;
        const int* t = c_tri[q];
        float* o = out + (size_t)FACES_OFF + (size_t)quad * 6u;
        *(f4a*)(o)     = (f4a){(float)(base + t[0]), (float)(base + t[1]),
                               (float)(base + t[2]), (float)(base + t[3])};
        *(f2a*)(o + 4) = (f2a){(float)(base + t[4]), (float)(base + t[5])};

    } else {
        // ---- verts: one thread = 4 elements ----
        unsigned i4 = ((bid - (MASK_BLOCKS + FACES_BLOCKS)) * 256u + tid) * 4u;
        if (i4 + 3u < VERTS_ELEMS) {
            float vals[4];
#pragma unroll
            for (int j = 0; j < 4; ++j) {
                unsigned idx = i4 + (unsigned)j;
                unsigned v = idx / 3u;
                unsigned c = idx - v * 3u;
                unsigned z = v / 9409u;
                unsigned r = v - z * 9409u;
                unsigned y = r / 97u;
                unsigned x = r - y * 97u;
                unsigned coord = (c == 0u) ? z : ((c == 1u) ? y : x);
                vals[j] = (float)coord - 0.5f;
            }
            *(float4*)(out + i4) = make_float4(vals[0], vals[1], vals[2], vals[3]);
        } else if (i4 < VERTS_ELEMS) {
            for (unsigned idx = i4; idx < VERTS_ELEMS; ++idx) {
                unsigned v = idx / 3u;
                unsigned c = idx - v * 3u;
                unsigned z = v / 9409u;
                unsigned r = v - z * 9409u;
                unsigned y = r / 97u;
                unsigned x = r - y * 97u;
                unsigned coord = (c == 0u) ? z : ((c == 1u) ? y : x);
                out[idx] = (float)coord - 0.5f;
            }
        }
    }
}

extern "C" void kernel_launch(void* const* d_in, const int* in_sizes, int n_in,
                              void* d_out, int out_size, void* d_ws, size_t ws_size,
                              hipStream_t stream) {
    const float* probas = (const float*)d_in[0];
    float* out = (float*)d_out;
    cubify_k<<<TOTAL_BLOCKS, 256, 0, stream>>>(probas, out);
}